// Round 13
// baseline (273.249 us; speedup 1.0000x reference)
//
#include <hip/hip_runtime.h>

// TransformerBlock on MI355X — round 12: ffn_k ported to the faithful m201
// 8-phase template: per-phase half-tile staging (6-7 phase prefetch leads),
// vmcnt(8) only at P0/P4, pre-barrier ds_reads, 2 barriers/phase, fixed
// even/odd tile buffers.

typedef __attribute__((ext_vector_type(8))) short short8;
typedef __attribute__((ext_vector_type(4))) float f32x4;

#define DEV __device__ __forceinline__

DEV unsigned short f2b(float f) {
  unsigned int u = __builtin_bit_cast(unsigned int, f);
  unsigned int r = u + 0x7fffu + ((u >> 16) & 1u);
  return (unsigned short)(r >> 16);
}
DEV float b2f(unsigned short h) {
  return __builtin_bit_cast(float, ((unsigned int)h) << 16);
}
DEV unsigned int cvtpk(float lo, float hi) {
  unsigned int r;
  asm("v_cvt_pk_bf16_f32 %0, %1, %2" : "=v"(r) : "v"(lo), "v"(hi));
  return r;
}
DEV f32x4 MFMA(short8 a, short8 b, f32x4 c) {
  return __builtin_amdgcn_mfma_f32_16x16x32_bf16(a, b, c, 0, 0, 0);
}
DEV void gload16(const void* g, void* lds) {
  __builtin_amdgcn_global_load_lds((const __attribute__((address_space(1))) void*)g,
                                   (__attribute__((address_space(3))) void*)lds, 16, 0, 0);
}

// ---------------- fused preprocessing: 5x f32->bf16 cvt + RoPE table + RMSNorm(x,g1) ----------------
__global__ __launch_bounds__(256) void prep_k(
    const float* __restrict__ wqkv, const float* __restrict__ wo,
    const float* __restrict__ w1, const float* __restrict__ w3,
    const float* __restrict__ w2,
    unsigned short* __restrict__ wqkv_b, unsigned short* __restrict__ wo_b,
    unsigned short* __restrict__ w1_b, unsigned short* __restrict__ w3_b,
    unsigned short* __restrict__ w2_b,
    float2* __restrict__ rtab,
    const float* __restrict__ x, const float* __restrict__ g1,
    unsigned short* __restrict__ yb) {
  const int bid = blockIdx.x;
  const int t = threadIdx.x;
  if (bid < 16384) {  // weight conversions
    const float* src;
    unsigned short* dst;
    int base;
    if (bid < 3072) { src = wqkv; dst = wqkv_b; base = bid; }
    else if (bid < 4096) { src = wo; dst = wo_b; base = bid - 3072; }
    else if (bid < 8192) { src = w1; dst = w1_b; base = bid - 4096; }
    else if (bid < 12288) { src = w3; dst = w3_b; base = bid - 8192; }
    else { src = w2; dst = w2_b; base = bid - 12288; }
    const int i = (base * 256 + t) * 4;
    float4 v = *(const float4*)(src + i);
    ushort4 o;
    o.x = f2b(v.x); o.y = f2b(v.y); o.z = f2b(v.z); o.w = f2b(v.w);
    *(ushort4*)(dst + i) = o;
  } else if (bid < 16640) {  // RoPE table
    const int i = (bid - 16384) * 256 + t;
    const int lt = i >> 5, pr = i & 31;
    const float invf = __expf((float)pr * -0.28782313662425572f);
    const float ang = (float)lt * invf;
    float sn, cs;
    sincosf(ang, &sn, &cs);
    rtab[i] = make_float2(cs, sn);
  } else {  // RMSNorm(x, g1) -> yb
    const int row = bid - 16640;
    const float4 v = *(const float4*)(x + (size_t)row * 1024 + t * 4);
    float ss = v.x * v.x + v.y * v.y + v.z * v.z + v.w * v.w;
#pragma unroll
    for (int m = 32; m >= 1; m >>= 1) ss += __shfl_xor(ss, m, 64);
    __shared__ float red[4];
    if ((t & 63) == 0) red[t >> 6] = ss;
    __syncthreads();
    float tot = red[0] + red[1] + red[2] + red[3];
    float inv = rsqrtf(tot * (1.0f / 1024.0f) + 1e-5f);
    ushort4 o;
    o.x = f2b(v.x * inv * g1[t * 4 + 0]);
    o.y = f2b(v.y * inv * g1[t * 4 + 1]);
    o.z = f2b(v.z * inv * g1[t * 4 + 2]);
    o.w = f2b(v.w * inv * g1[t * 4 + 3]);
    *(ushort4*)(yb + (size_t)row * 1024 + t * 4) = o;
  }
}

// ---------------- RMSNorm: f32 in, bf16 out (rows of 1024) ----------------
__global__ __launch_bounds__(256) void rms_k(const float* __restrict__ x,
                                             const float* __restrict__ g,
                                             unsigned short* __restrict__ out) {
  const int row = blockIdx.x;
  const int t = threadIdx.x;
  const float4 v = *(const float4*)(x + (size_t)row * 1024 + t * 4);
  float ss = v.x * v.x + v.y * v.y + v.z * v.z + v.w * v.w;
#pragma unroll
  for (int m = 32; m >= 1; m >>= 1) ss += __shfl_xor(ss, m, 64);
  __shared__ float red[4];
  if ((t & 63) == 0) red[t >> 6] = ss;
  __syncthreads();
  float tot = red[0] + red[1] + red[2] + red[3];
  float inv = rsqrtf(tot * (1.0f / 1024.0f) + 1e-5f);
  ushort4 o;
  o.x = f2b(v.x * inv * g[t * 4 + 0]);
  o.y = f2b(v.y * inv * g[t * 4 + 1]);
  o.z = f2b(v.z * inv * g[t * 4 + 2]);
  o.w = f2b(v.w * inv * g[t * 4 + 3]);
  *(ushort4*)(out + (size_t)row * 1024 + t * 4) = o;
}

// ---------------- pipelined 128² GEMM: C[M][N] = A[M][K] * B[N][K]^T ----------------
template <int MODE>
__global__ __launch_bounds__(256, 3) void gemm_bt(
    const unsigned short* __restrict__ A, const unsigned short* __restrict__ B0,
    int M, int N, int K,
    float* __restrict__ outF, const float* __restrict__ resid,
    unsigned short* __restrict__ q, unsigned short* __restrict__ k2,
    unsigned short* __restrict__ v,
    const float2* __restrict__ rtab) {
  __shared__ __align__(16) unsigned short As[2][128 * 32];
  __shared__ __align__(16) unsigned short Bs[2][128 * 32];
  const int t = threadIdx.x;
  const int wv = t >> 6, ln = t & 63;
  const int l15 = ln & 15, grp = ln >> 4;
  const int wr = wv >> 1, wc = wv & 1;
  int m0, n0;
  if constexpr (MODE == 1) {
    const int d = blockIdx.y * 8 + blockIdx.x;
    const int xcd = d & 7, j = d >> 3;
    m0 = (xcd * 4 + (j >> 3)) * 128;
    n0 = (j & 7) * 128;
  } else {
    m0 = blockIdx.y * 128;
    n0 = blockIdx.x * 128;
  }

  const char* sA0 = (const char*)A + ((size_t)(m0 + (t >> 2)) * K + (t & 3) * 8) * 2;
  const char* sA1 = (const char*)A + ((size_t)(m0 + 64 + (t >> 2)) * K + (t & 3) * 8) * 2;
  const char* sB0 = (const char*)B0 + ((size_t)(n0 + (t >> 2)) * K + (t & 3) * 8) * 2;
  const char* sB1 = (const char*)B0 + ((size_t)(n0 + 64 + (t >> 2)) * K + (t & 3) * 8) * 2;

  f32x4 acc[4][4];
#pragma unroll
  for (int mm = 0; mm < 4; ++mm)
#pragma unroll
    for (int nn = 0; nn < 4; ++nn) acc[mm][nn] = (f32x4){0.f, 0.f, 0.f, 0.f};

  const int KT = K >> 5;
  gload16(sA0, (char*)As[0] + wv * 1024);
  gload16(sA1, (char*)As[0] + 4096 + wv * 1024);
  gload16(sB0, (char*)Bs[0] + wv * 1024);
  gload16(sB1, (char*)Bs[0] + 4096 + wv * 1024);

#pragma unroll 1
  for (int kt = 0; kt < KT; ++kt) {
    const int par = kt & 1;
    const size_t ko = (size_t)((kt + 1 < KT) ? (kt + 1) : kt) * 64;  // bytes
    gload16(sA0 + ko, (char*)As[par ^ 1] + wv * 1024);
    gload16(sA1 + ko, (char*)As[par ^ 1] + 4096 + wv * 1024);
    gload16(sB0 + ko, (char*)Bs[par ^ 1] + wv * 1024);
    gload16(sB1 + ko, (char*)Bs[par ^ 1] + 4096 + wv * 1024);
    asm volatile("s_waitcnt vmcnt(4)" ::: "memory");
    __builtin_amdgcn_s_barrier();
    const unsigned short* Ab = As[par];
    const unsigned short* Bb = Bs[par];
    short8 af[4], bf0[4];
#pragma unroll
    for (int mm = 0; mm < 4; ++mm)
      af[mm] = *(const short8*)&Ab[(wr * 64 + mm * 16 + l15) * 32 + grp * 8];
#pragma unroll
    for (int nn = 0; nn < 4; ++nn)
      bf0[nn] = *(const short8*)&Bb[(wc * 64 + nn * 16 + l15) * 32 + grp * 8];
#pragma unroll
    for (int mm = 0; mm < 4; ++mm)
#pragma unroll
      for (int nn = 0; nn < 4; ++nn) acc[mm][nn] = MFMA(af[mm], bf0[nn], acc[mm][nn]);
    __builtin_amdgcn_s_barrier();
  }

#pragma unroll
  for (int mm = 0; mm < 4; ++mm)
#pragma unroll
    for (int nn = 0; nn < 4; ++nn)
#pragma unroll
      for (int j = 0; j < 4; ++j) {
        const int r = m0 + wr * 64 + mm * 16 + grp * 4 + j;
        const int c = n0 + wc * 64 + nn * 16 + l15;
        float val = acc[mm][nn][j];
        if constexpr (MODE == 0) {
          const int mat = c >> 10;
          const int rem = c & 1023;
          const int hh = rem >> 6;
          const int dh = rem & 63;
          const int bt = r >> 11;
          const int lt = r & 2047;
          float outv = val;
          if (mat < 2) {  // RoPE on q,k via table
            const float partner = __shfl_xor(val, 1, 64);
            const float2 cs = rtab[lt * 32 + (dh >> 1)];
            outv = (dh & 1) ? (val * cs.x + partner * cs.y) : (val * cs.x - partner * cs.y);
          }
          if (mat == 0) outv *= 0.18033688011112042f;  // 0.125 * log2(e)
          unsigned short* dst = (mat == 0) ? q : ((mat == 1) ? k2 : v);
          dst[((size_t)(bt * 16 + hh) * 2048 + lt) * 64 + dh] = f2b(outv);
        } else {
          const size_t idx = (size_t)r * N + c;
          outF[idx] = resid[idx] + val;
        }
      }
}

// ---------------- W2 split-K chunk GEMM (S=2, chunk K=2048) ----------------
__global__ __launch_bounds__(256, 3) void gemm_sk(
    const unsigned short* __restrict__ A, const unsigned short* __restrict__ B0,
    unsigned short* __restrict__ part) {
  __shared__ __align__(16) unsigned short As[2][128 * 32];
  __shared__ __align__(16) unsigned short Bs[2][128 * 32];
  const int t = threadIdx.x;
  const int wv = t >> 6, ln = t & 63;
  const int l15 = ln & 15, grp = ln >> 4;
  const int wr = wv >> 1, wc = wv & 1;
  const int d = blockIdx.y * 8 + blockIdx.x;
  const int xcd = d & 7, j = d >> 3;
  const int m0 = (xcd * 4 + (j >> 3)) * 128;
  const int n0 = (j & 7) * 128;
  const size_t kbase = (size_t)blockIdx.z * 2048;

  const char* sA0 = (const char*)A + ((size_t)(m0 + (t >> 2)) * 4096 + kbase + (t & 3) * 8) * 2;
  const char* sA1 = (const char*)A + ((size_t)(m0 + 64 + (t >> 2)) * 4096 + kbase + (t & 3) * 8) * 2;
  const char* sB0 = (const char*)B0 + ((size_t)(n0 + (t >> 2)) * 4096 + kbase + (t & 3) * 8) * 2;
  const char* sB1 = (const char*)B0 + ((size_t)(n0 + 64 + (t >> 2)) * 4096 + kbase + (t & 3) * 8) * 2;

  f32x4 acc[4][4];
#pragma unroll
  for (int mm = 0; mm < 4; ++mm)
#pragma unroll
    for (int nn = 0; nn < 4; ++nn) acc[mm][nn] = (f32x4){0.f, 0.f, 0.f, 0.f};

  gload16(sA0, (char*)As[0] + wv * 1024);
  gload16(sA1, (char*)As[0] + 4096 + wv * 1024);
  gload16(sB0, (char*)Bs[0] + wv * 1024);
  gload16(sB1, (char*)Bs[0] + 4096 + wv * 1024);

#pragma unroll 1
  for (int kt = 0; kt < 64; ++kt) {
    const int par = kt & 1;
    const size_t ko = (size_t)((kt + 1 < 64) ? (kt + 1) : kt) * 64;
    gload16(sA0 + ko, (char*)As[par ^ 1] + wv * 1024);
    gload16(sA1 + ko, (char*)As[par ^ 1] + 4096 + wv * 1024);
    gload16(sB0 + ko, (char*)Bs[par ^ 1] + wv * 1024);
    gload16(sB1 + ko, (char*)Bs[par ^ 1] + 4096 + wv * 1024);
    asm volatile("s_waitcnt vmcnt(4)" ::: "memory");
    __builtin_amdgcn_s_barrier();
    const unsigned short* Ab = As[par];
    const unsigned short* Bb = Bs[par];
    short8 af[4], bf0[4];
#pragma unroll
    for (int mm = 0; mm < 4; ++mm)
      af[mm] = *(const short8*)&Ab[(wr * 64 + mm * 16 + l15) * 32 + grp * 8];
#pragma unroll
    for (int nn = 0; nn < 4; ++nn)
      bf0[nn] = *(const short8*)&Bb[(wc * 64 + nn * 16 + l15) * 32 + grp * 8];
#pragma unroll
    for (int mm = 0; mm < 4; ++mm)
#pragma unroll
      for (int nn = 0; nn < 4; ++nn) acc[mm][nn] = MFMA(af[mm], bf0[nn], acc[mm][nn]);
    __builtin_amdgcn_s_barrier();
  }

  unsigned short* pz = part + (size_t)blockIdx.z * 4194304;
#pragma unroll
  for (int mm = 0; mm < 4; ++mm)
#pragma unroll
    for (int nn = 0; nn < 4; ++nn)
#pragma unroll
      for (int j = 0; j < 4; ++j) {
        const int r = m0 + wr * 64 + mm * 16 + grp * 4 + j;
        const int c = n0 + wc * 64 + nn * 16 + l15;
        pz[(size_t)r * 1024 + c] = f2b(acc[mm][nn][j]);
      }
}

// ---------------- reduce: out = x2 + sum of 2 bf16 partials ----------------
__global__ __launch_bounds__(256) void red_k(const float* __restrict__ x2,
                                             const unsigned short* __restrict__ part,
                                             float* __restrict__ out) {
  const int i = (blockIdx.x * 256 + threadIdx.x) * 4;
  float4 r = *(const float4*)(x2 + i);
#pragma unroll
  for (int z = 0; z < 2; ++z) {
    const ushort4 p = *(const ushort4*)(part + (size_t)z * 4194304 + i);
    r.x += b2f(p.x);
    r.y += b2f(p.y);
    r.z += b2f(p.z);
    r.w += b2f(p.w);
  }
  *(float4*)(out + i) = r;
}

// ---------------- FFN dual-GEMM: 256x256(Bv), m201 8-phase template ----------------
// Iteration = 2 K-tiles: E (even, buf0) and O (odd, buf1). One half-tile staged
// per phase: P0:A1(O) P1:A0(E+2) P2:B0(E+2) P3:B1(E+2) P4:A1(E+2) P5:A0(O+2)
// P6:B0(O+2) P7:B1(O+2) -> every half-tile has 6-7 phases of flight.
// vmcnt(8) only at P0/P4 (guarantees exactly the 4 half-tiles consumed next).
// Reads pre-barrier at P1/P2/P5/P6; post-barrier at P0/P4 (other waves' vmcnt).
__global__ __launch_bounds__(512, 2) void ffn_k(
    const unsigned short* __restrict__ A, const unsigned short* __restrict__ B0,
    const unsigned short* __restrict__ B1, unsigned short* __restrict__ outH) {
  __shared__ __align__(16) char Asm[2][32768];
  __shared__ __align__(16) char Bsm[2][32768];
  const int t = threadIdx.x;
  const int wid = t >> 6, lane = t & 63;
  const int l15 = lane & 15, grp = lane >> 4;
  const int wr = wid >> 2, wc = wid & 3;
  const int d = blockIdx.x;
  const int xcd = d & 7, r8 = d >> 3;
  const int m0 = (r8 >> 2) * 256;             // 16 m-panels
  const int n0 = (xcd * 4 + (r8 & 3)) * 256;  // 32 n-panels, 4 per XCD

  // staging sources: shot s -> srcA0 + s*131072 / srcB0 + s*65536 (+ koff bytes)
  const char* srcA0;
  const char* srcB0;
  {
    const int lb = t * 16;
    const int r = lb >> 7;  // t>>3
    const int sw = (((lb >> 4) & 7) * 16) ^ ((r & 7) << 4);
    srcA0 = (const char*)A + (size_t)(m0 + r) * 2048 + sw;
    const int R = n0 + r;
    const unsigned short* bsrc = ((R >> 4) & 1) ? B1 : B0;
    const int br = ((R >> 5) << 4) + (R & 15);
    srcB0 = (const char*)bsrc + (size_t)br * 2048 + sw;
  }
  char* const ldsA = (char*)Asm + wid * 1024;  // + buf*32768 + shot*8192
  char* const ldsB = (char*)Bsm + wid * 1024;

  f32x4 acc[8][4];
#pragma unroll
  for (int m = 0; m < 8; ++m)
#pragma unroll
    for (int n = 0; n < 4; ++n) acc[m][n] = (f32x4){0.f, 0.f, 0.f, 0.f};

  // prologue issue stream: A0(0),B0(0),B1(0),A1(0),A0(1),B0(1),B1(1)
  gload16(srcA0 + 0 * 131072, ldsA + 0 * 8192);
  gload16(srcA0 + 1 * 131072, ldsA + 1 * 8192);
  gload16(srcB0 + 0 * 65536, ldsB + 0 * 8192);
  gload16(srcB0 + 1 * 65536, ldsB + 1 * 8192);
  gload16(srcB0 + 2 * 65536, ldsB + 2 * 8192);
  gload16(srcB0 + 3 * 65536, ldsB + 3 * 8192);
  gload16(srcA0 + 2 * 131072, ldsA + 2 * 8192);
  gload16(srcA0 + 3 * 131072, ldsA + 3 * 8192);
  gload16(srcA0 + 0 * 131072 + 128, ldsA + 32768 + 0 * 8192);
  gload16(srcA0 + 1 * 131072 + 128, ldsA + 32768 + 1 * 8192);
  gload16(srcB0 + 0 * 65536 + 128, ldsB + 32768 + 0 * 8192);
  gload16(srcB0 + 1 * 65536 + 128, ldsB + 32768 + 1 * 8192);
  gload16(srcB0 + 2 * 65536 + 128, ldsB + 32768 + 2 * 8192);
  gload16(srcB0 + 3 * 65536 + 128, ldsB + 32768 + 3 * 8192);

  const int rA0 = wr * 64 + l15;
  const int rB0 = wc * 32 + l15;
  const char* const AbE = Asm[0];
  const char* const BbE = Bsm[0];
  const char* const AbO = Asm[1];
  const char* const BbO = Bsm[1];

  short8 a0[2][4], a1[2][4], b0[2][2], b1[2][2];

#pragma unroll 1
  for (int it = 0; it < 8; ++it) {
    const size_t kO = (size_t)(2 * it + 1) * 128;
    const int e2 = (2 * it + 2 < 16) ? (2 * it + 2) : 15;
    const int o2 = (2 * it + 3 < 16) ? (2 * it + 3) : 15;
    const size_t kE2 = (size_t)e2 * 128;
    const size_t kO2 = (size_t)o2 * 128;

    // ---- P0: stage A1(O); vmcnt(8); barrier; read a0,b0(E); MFMA q00(E) ----
    gload16(srcA0 + 2 * 131072 + kO, ldsA + 32768 + 2 * 8192);
    gload16(srcA0 + 3 * 131072 + kO, ldsA + 32768 + 3 * 8192);
    asm volatile("s_waitcnt vmcnt(8)" ::: "memory");
    __builtin_amdgcn_s_barrier();
#pragma unroll
    for (int ks = 0; ks < 2; ++ks)
#pragma unroll
      for (int m = 0; m < 4; ++m) {
        const int r = rA0 + m * 16;
        a0[ks][m] = *(const short8*)(AbE + r * 128 + ((ks * 64 + grp * 16) ^ ((r & 7) << 4)));
      }
#pragma unroll
    for (int ks = 0; ks < 2; ++ks)
#pragma unroll
      for (int n = 0; n < 2; ++n) {
        const int r = rB0 + n * 16;
        b0[ks][n] = *(const short8*)(BbE + r * 128 + ((ks * 64 + grp * 16) ^ ((r & 7) << 4)));
      }
    __builtin_amdgcn_s_setprio(1);
#pragma unroll
    for (int ks = 0; ks < 2; ++ks)
#pragma unroll
      for (int m = 0; m < 4; ++m)
#pragma unroll
        for (int n = 0; n < 2; ++n) acc[m][n] = MFMA(a0[ks][m], b0[ks][n], acc[m][n]);
    __builtin_amdgcn_s_setprio(0);
    __builtin_amdgcn_s_barrier();

    // ---- P1: read b1(E); stage A0(E+2); barrier; MFMA q01(E) ----
#pragma unroll
    for (int ks = 0; ks < 2; ++ks)
#pragma unroll
      for (int n = 0; n < 2; ++n) {
        const int r = 128 + rB0 + n * 16;
        b1[ks][n] = *(const short8*)(BbE + r * 128 + ((ks * 64 + grp * 16) ^ ((r & 7) << 4)));
      }
    gload16(srcA0 + 0 * 131072 + kE2, ldsA + 0 * 8192);
    gload16(srcA0 + 1 * 131072 + kE2, ldsA + 1 * 8192);
    __builtin_amdgcn_s_barrier();
    __builtin_amdgcn_s_setprio(1);
#pragma unroll
    for (int ks = 0; ks < 2; ++ks)
#pragma unroll
      for (int m = 0; m < 4; ++m)
#pragma unroll
        for (int n = 0; n < 2; ++n) acc[m][2 + n] = MFMA(a0[ks][m], b1[ks][n], acc[m][2 + n]);
    __builtin_amdgcn_s_setprio(0);
    __builtin_amdgcn_s_barrier();

    // ---- P2: read a1(E); stage B0(E+2); barrier; MFMA q11(E) ----
#pragma unroll
    for (int ks = 0; ks < 2; ++ks)
#pragma unroll
      for (int m = 0; m < 4; ++m) {
        const int r = 128 + rA0 + m * 16;
        a1[ks][m] = *(const short8*)(AbE + r * 128 + ((ks * 64 + grp * 16) ^ ((r & 7) << 4)));
      }
    gload16(srcB0 + 0 * 65536 + kE2, ldsB + 0 * 8192);
    gload16(srcB0 + 1 * 65536 + kE2, ldsB + 1 * 8192);
    __builtin_amdgcn_s_barrier();
    __builtin_amdgcn_s_setprio(1);
#pragma unroll
    for (int ks = 0; ks < 2; ++ks)
#pragma unroll
      for (int m = 0; m < 4; ++m)
#pragma unroll
        for (int n = 0; n < 2; ++n) acc[4 + m][2 + n] = MFMA(a1[ks][m], b1[ks][n], acc[4 + m][2 + n]);
    __builtin_amdgcn_s_setprio(0);
    __builtin_amdgcn_s_barrier();

    // ---- P3: stage B1(E+2); barrier; MFMA q10(E) ----
    gload16(srcB0 + 2 * 65536 + kE2, ldsB + 2 * 8192);
    gload16(srcB0 + 3 * 65536 + kE2, ldsB + 3 * 8192);
    __builtin_amdgcn_s_barrier();
    __builtin_amdgcn_s_setprio(1);
#pragma unroll
    for (int ks = 0; ks < 2; ++ks)
#pragma unroll
      for (int m = 0; m < 4; ++m)
#pragma unroll
        for (int n = 0; n < 2; ++n) acc[4 + m][n] = MFMA(a1[ks][m], b0[ks][n], acc[4 + m][n]);
    __builtin_amdgcn_s_setprio(0);
    __builtin_amdgcn_s_barrier();

    // ---- P4: stage A1(E+2); vmcnt(8); barrier; read a0,b0(O); MFMA q00(O) ----
    gload16(srcA0 + 2 * 131072 + kE2, ldsA + 2 * 8192);
    gload16(srcA0 + 3 * 131072 + kE2, ldsA + 3 * 8192);
    asm volatile("s_waitcnt vmcnt(8)" ::: "memory");
    __builtin_amdgcn_s_barrier();
#pragma unroll
    for (int ks = 0; ks < 2; ++ks)
#pragma unroll
      for (int m = 0; m < 4; ++m) {
        const int r = rA0 + m * 16;
        a0[ks][m] = *(const short8*)(AbO + r * 128 + ((ks * 64 + grp * 16) ^ ((r & 7) << 4)));
      }
#pragma unroll
    for (int ks = 0; ks < 2; ++ks)
#pragma unroll
      for (int n = 0; n < 2; ++n) {
        const int r = rB0 + n * 16;
        b0[ks][n] = *(const short8*)(BbO + r * 128 + ((ks * 64 + grp * 16) ^ ((r & 7) << 4)));
      }
    __builtin_amdgcn_s_setprio(1);
#pragma unroll
    for (int ks = 0; ks < 2; ++ks)
#pragma unroll
      for (int m = 0; m < 4; ++m)
#pragma unroll
        for (int n = 0; n < 2; ++n) acc[m][n] = MFMA(a0[ks][m], b0[ks][n], acc[m][n]);
    __builtin_amdgcn_s_setprio(0);
    __builtin_amdgcn_s_barrier();

    // ---- P5: read b1(O); stage A0(O+2); barrier; MFMA q01(O) ----
#pragma unroll
    for (int ks = 0; ks < 2; ++ks)
#pragma unroll
      for (int n = 0; n < 2; ++n) {
        const int r = 128 + rB0 + n * 16;
        b1[ks][n] = *(const short8*)(BbO + r * 128 + ((ks * 64 + grp * 16) ^ ((r & 7) << 4)));
      }
    gload16(srcA0 + 0 * 131072 + kO2, ldsA + 32768 + 0 * 8192);
    gload16(srcA0 + 1 * 131072 + kO2, ldsA + 32768 + 1 * 8192);
    __builtin_amdgcn_s_barrier();
    __builtin_amdgcn_s_setprio(1);
#pragma unroll
    for (int ks = 0; ks < 2; ++ks)
#pragma unroll
      for (int m = 0; m < 4; ++m)
#pragma unroll
        for (int n = 0; n < 2; ++n) acc[m][2 + n] = MFMA(a0[ks][m], b1[ks][n], acc[m][2 + n]);
    __builtin_amdgcn_s_setprio(0);
    __builtin_amdgcn_s_barrier();

    // ---- P6: read a1(O); stage B0(O+2); barrier; MFMA q11(O) ----
#pragma unroll
    for (int ks = 0; ks < 2; ++ks)
#pragma unroll
      for (int m = 0; m < 4; ++m) {
        const int r = 128 + rA0 + m * 16;
        a1[ks][m] = *(const short8*)(AbO + r * 128 + ((ks * 64 + grp * 16) ^ ((r & 7) << 4)));
      }
    gload16(srcB0 + 0 * 65536 + kO2, ldsB + 32768 + 0 * 8192);
    gload16(srcB0 + 1 * 65536 + kO2, ldsB + 32768 + 1 * 8192);
    __builtin_amdgcn_s_barrier();
    __builtin_amdgcn_s_setprio(1);
#pragma unroll
    for (int ks = 0; ks < 2; ++ks)
#pragma unroll
      for (int m = 0; m < 4; ++m)
#pragma unroll
        for (int n = 0; n < 2; ++n) acc[4 + m][2 + n] = MFMA(a1[ks][m], b1[ks][n], acc[4 + m][2 + n]);
    __builtin_amdgcn_s_setprio(0);
    __builtin_amdgcn_s_barrier();

    // ---- P7: stage B1(O+2); barrier; MFMA q10(O) ----
    gload16(srcB0 + 2 * 65536 + kO2, ldsB + 32768 + 2 * 8192);
    gload16(srcB0 + 3 * 65536 + kO2, ldsB + 32768 + 3 * 8192);
    __builtin_amdgcn_s_barrier();
    __builtin_amdgcn_s_setprio(1);
#pragma unroll
    for (int ks = 0; ks < 2; ++ks)
#pragma unroll
      for (int m = 0; m < 4; ++m)
#pragma unroll
        for (int n = 0; n < 2; ++n) acc[4 + m][n] = MFMA(a1[ks][m], b0[ks][n], acc[4 + m][n]);
    __builtin_amdgcn_s_setprio(0);
    __builtin_amdgcn_s_barrier();
  }

#pragma unroll
  for (int mh = 0; mh < 2; ++mh)
#pragma unroll
    for (int m = 0; m < 4; ++m)
#pragma unroll
      for (int nh = 0; nh < 2; ++nh)
#pragma unroll
        for (int j = 0; j < 4; ++j) {
          const int row = m0 + mh * 128 + wr * 64 + m * 16 + grp * 4 + j;
          const int ch = (n0 >> 1) + nh * 64 + wc * 16 + l15;
          const float a1v = acc[mh * 4 + m][nh * 2 + 0][j];
          const float a3v = acc[mh * 4 + m][nh * 2 + 1][j];
          const float hval = a1v / (1.0f + __expf(-a1v)) * a3v;
          outH[(size_t)row * 4096 + ch] = f2b(hval);
        }
}

// ---------------- V transpose: vb[bh][lt][dh] -> vt[bh][dh][lt] ----------------
__global__ __launch_bounds__(256) void vtr_k(const unsigned short* __restrict__ v,
                                             unsigned short* __restrict__ vt) {
  __shared__ __align__(16) unsigned short tile[64][72];
  const int bh = blockIdx.y;
  const int lt0 = blockIdx.x * 64;
  const int t = threadIdx.x;
  const int r = t >> 2;
  const int c0 = (t & 3) * 16;
  const unsigned short* src = v + ((size_t)bh * 2048 + lt0 + r) * 64 + c0;
  *(short8*)&tile[r][c0] = *(const short8*)src;
  *(short8*)&tile[r][c0 + 8] = *(const short8*)(src + 8);
  __syncthreads();
  unsigned short outv[16];
#pragma unroll
  for (int i = 0; i < 16; ++i) outv[i] = tile[c0 + i][r];
  unsigned short* dst = vt + ((size_t)bh * 64 + r) * 2048 + lt0 + c0;
  *(short8*)dst = *(short8*)&outv[0];
  *(short8*)(dst + 8) = *(short8*)&outv[8];
}

// ---------------- causal flash attention: 4 waves, QBLK=64, KVBLK=64 ----------------
__global__ __launch_bounds__(256) void attn_k(const unsigned short* __restrict__ qb,
                                              const unsigned short* __restrict__ kb,
                                              const unsigned short* __restrict__ vt,
                                              unsigned short* __restrict__ yh) {
  const int dd = blockIdx.x;  // 512 blocks: all 16 pairs of a head on one XCD
  const int xcd = dd & 7, idx = dd >> 3;
  const int bh = xcd + 8 * (idx & 3);
  const int pair = idx >> 2;  // 0..15
  const int t = threadIdx.x;
  const int w = t >> 6, lane = t & 63;
  const int l15 = lane & 15, grp = lane >> 4;

  __shared__ __align__(16) char Ks[2][8192];
  __shared__ __align__(16) char Vs[2][8192];
  __shared__ __align__(16) char Ps[8192];
  char* Pw = Ps + w * 2048;

  const char* kg = (const char*)kb + (size_t)bh * 262144;
  const char* vg = (const char*)vt + (size_t)bh * 262144;

  const int lb0 = t * 16, lb1 = 4096 + t * 16;
  const int r0 = lb0 >> 7, r1 = lb1 >> 7;
  const int sl0 = (lb0 & 0x70) ^ ((r0 & 7) << 4);
  const int sl1 = (lb1 & 0x70) ^ ((r1 & 7) << 4);
  const char* srcK0 = kg + r0 * 128 + sl0;
  const char* srcK1 = kg + r1 * 128 + sl1;
  const char* srcV0 = vg + (size_t)r0 * 4096 + sl0;
  const char* srcV1 = vg + (size_t)r1 * 4096 + sl1;

  const int bq = bh >> 4, hh = bh & 15;

#pragma unroll 1
  for (int half = 0; half < 2; ++half) {
    const int qblk = half ? pair : (31 - pair);
    const int qw = qblk * 64 + w * 16;

    const unsigned short* qp = qb + ((size_t)bh * 2048 + qw) * 64;
    const short8 qf0 = *(const short8*)(qp + l15 * 64 + grp * 8);
    const short8 qf1 = *(const short8*)(qp + l15 * 64 + 32 + grp * 8);

    f32x4 o[4];
#pragma unroll
    for (int d = 0; d < 4; ++d) o[d] = (f32x4){0.f, 0.f, 0.f, 0.f};
    float mrun = -3.0e38f, lrun = 0.f;  // per-lane: q = qw + l15

    const int nkt = qblk + 1;

    __syncthreads();
    {
      gload16(srcK0, Ks[0] + w * 1024);
      gload16(srcK1, Ks[0] + 4096 + w * 1024);
      gload16(srcV0, Vs[0] + w * 1024);
      gload16(srcV1, Vs[0] + 4096 + w * 1024);
    }

#pragma unroll 1
    for (int kt = 0; kt < nkt; ++kt) {
      const int par = kt & 1;
      const int ktn = (kt + 1 < nkt) ? (kt + 1) : kt;
      gload16(srcK0 + (size_t)ktn * 8192, Ks[par ^ 1] + w * 1024);
      gload16(srcK1 + (size_t)ktn * 8192, Ks[par ^ 1] + 4096 + w * 1024);
      gload16(srcV0 + ktn * 128, Vs[par ^ 1] + w * 1024);
      gload16(srcV1 + ktn * 128, Vs[par ^ 1] + 4096 + w * 1024);
      asm volatile("s_waitcnt vmcnt(4)" ::: "memory");
      __builtin_amdgcn_s_barrier();

      const char* Kc = Ks[par];
      const char* Vc = Vs[par];

      // swapped QK^T: st[c][j] = S^T[k = 16c + 4*grp + j][q = l15] (log2 domain)
      f32x4 st[4];
#pragma unroll
      for (int c = 0; c < 4; ++c) {
        const int r = c * 16 + l15;
        const int xr = (r & 7) << 4;
        const short8 kf0 = *(const short8*)(Kc + r * 128 + ((grp * 16) ^ xr));
        const short8 kf1 = *(const short8*)(Kc + r * 128 + ((64 + grp * 16) ^ xr));
        f32x4 z = (f32x4){0.f, 0.f, 0.f, 0.f};
        __builtin_amdgcn_s_setprio(1);
        z = MFMA(kf0, qf0, z);
        z = MFMA(kf1, qf1, z);
        __builtin_amdgcn_s_setprio(0);
        st[c] = z;
      }

      const bool diag = (kt == qblk);
      const int qg = qw + l15;
      float av[4][4];
      float tm = -3.0e38f;
#pragma unroll
      for (int c = 0; c < 4; ++c)
#pragma unroll
        for (int j = 0; j < 4; ++j) {
          float x = st[c][j];
          if (diag) {
            const int kg2 = kt * 64 + c * 16 + grp * 4 + j;
            if (kg2 > qg) x = -3.0e38f;
          }
          av[c][j] = x;
          tm = fmaxf(tm, x);
        }
      tm = fmaxf(tm, __shfl_xor(tm, 16, 64));
      tm = fmaxf(tm, __shfl_xor(tm, 32, 64));

      const float mold = mrun;
      const bool need = tm > mold;
      mrun = fmaxf(mold, tm);
      const float aown = need ? __builtin_amdgcn_exp2f(mold - mrun) : 1.0f;
      if (__any(need)) {  // wave-uniform
        float am[4];
#pragma unroll
        for (int j = 0; j < 4; ++j) am[j] = __shfl(aown, grp * 4 + j, 64);
#pragma unroll
        for (int d = 0; d < 4; ++d)
#pragma unroll
          for (int j = 0; j < 4; ++j) o[d][j] *= am[j];
      }

      float rs = 0.f;
      uint2 pk[4];
#pragma unroll
      for (int c = 0; c < 4; ++c) {
        const float p0 = __builtin_amdgcn_exp2f(av[c][0] - mrun);
        const float p1 = __builtin_amdgcn_exp2f(av[c][1] - mrun);
        const float p2 = __builtin_amdgcn_exp2f(av[c][2] - mrun);
        const float p3 = __builtin_amdgcn_exp2f(av[c][3] - mrun);
        rs += (p0 + p1) + (p2 + p3);
        pk[c].x = cvtpk(p0, p1);
        pk[c].y = cvtpk(p2, p3);
      }
      rs += __shfl_xor(rs, 16, 64);
      rs += __shfl_xor(rs, 32, 64);
      lrun = lrun * aown + rs;

      // write P row q=l15: 4x b64, k-quads at (2k)^xor (consistent with b128 read)
      const int xp = (l15 & 7) << 4;
      char* prow = Pw + l15 * 128;
#pragma unroll
      for (int c = 0; c < 4; ++c)
        *(uint2*)(prow + ((32 * c + 8 * grp) ^ xp)) = pk[c];

      // PV: A = P rows, B = V^T rows
      const short8 pa0 = *(const short8*)(prow + ((grp * 16) ^ xp));
      const short8 pa1 = *(const short8*)(prow + ((64 + grp * 16) ^ xp));
#pragma unroll
      for (int db = 0; db < 4; ++db) {
        const int rv = db * 16 + l15;
        const int xv = (rv & 7) << 4;
        const short8 vf0 = *(const short8*)(Vc + rv * 128 + ((grp * 16) ^ xv));
        const short8 vf1 = *(const short8*)(Vc + rv * 128 + ((64 + grp * 16) ^ xv));
        __builtin_amdgcn_s_setprio(1);
        o[db] = MFMA(pa0, vf0, o[db]);
        o[db] = MFMA(pa1, vf1, o[db]);
        __builtin_amdgcn_s_setprio(0);
      }
      __builtin_amdgcn_s_barrier();
    }

    float lr[4];
#pragma unroll
    for (int j = 0; j < 4; ++j) lr[j] = __shfl(lrun, grp * 4 + j, 64);
#pragma unroll
    for (int db = 0; db < 4; ++db)
#pragma unroll
      for (int j = 0; j < 4; ++j) {
        const float valo = o[db][j] / lr[j];
        const size_t rowo = (size_t)bq * 2048 + qw + grp * 4 + j;
        yh[rowo * 1024 + hh * 64 + db * 16 + l15] = f2b(valo);
      }
  }
}

extern "C" void kernel_launch(void* const* d_in, const int* in_sizes, int n_in,
                              void* d_out, int out_size, void* d_ws, size_t ws_size,
                              hipStream_t stream) {
  const float* x = (const float*)d_in[0];
  const float* wqkv = (const float*)d_in[1];
  const float* wo = (const float*)d_in[2];
  const float* w1 = (const float*)d_in[3];
  const float* w2 = (const float*)d_in[4];
  const float* w3 = (const float*)d_in[5];
  const float* g1 = (const float*)d_in[6];
  const float* g2 = (const float*)d_in[7];

  // Workspace layout (88 MB), lifetimes annotated:
  char* ws = (char*)d_ws;
  unsigned short* wqkv_b = (unsigned short*)(ws + 0);         // 6 MB  [prep -> qkv]
  unsigned short* wo_b = (unsigned short*)(ws + 6291456);     // 2 MB  [prep -> wo]
  unsigned short* w1_b = (unsigned short*)(ws + 8388608);     // 8 MB  [prep -> ffn]
  unsigned short* w3_b = (unsigned short*)(ws + 16777216);    // 8 MB  [prep -> ffn]
  unsigned short* yb = (unsigned short*)(ws + 25165824);      // 8 MB  [prep/rms -> qkv/ffn]
  float* x2 = (float*)(ws + 33554432);                        // 16 MB [wo -> red]
  float2* rtab = (float2*)(ws + 33554432);                    // aliases x2, dead before wo
  unsigned short* w2_b = (unsigned short*)(ws + 50331648);    // 8 MB  [prep -> gemm_sk]
  unsigned short* qb = (unsigned short*)(ws + 58720256);      // 8 MB  [qkv -> attn]
  unsigned short* kb = (unsigned short*)(ws + 67108864);      // 8 MB  [qkv -> attn]
  unsigned short* vb = (unsigned short*)(ws + 75497472);      // 8 MB  [qkv -> vtr]
  unsigned short* vt = (unsigned short*)(ws + 83886080);      // 8 MB  [vtr -> attn]
  unsigned short* yh = vb;                                    // attn out reuses dead vb
  unsigned short* hb = (unsigned short*)(ws + 58720256);      // 32 MB [ffn -> gemm_sk], over dead q/k/v/vt
  unsigned short* part = (unsigned short*)(ws + 0);           // 16 MB [gemm_sk -> red], over dead weights
  if (ws_size < 92274688) return;

  prep_k<<<20736, 256, 0, stream>>>(wqkv, wo, w1, w3, w2,
                                    wqkv_b, wo_b, w1_b, w3_b, w2_b,
                                    rtab, x, g1, yb);
  gemm_bt<0><<<dim3(24, 32), 256, 0, stream>>>(yb, wqkv_b, 4096, 3072, 1024,
                                               nullptr, nullptr, qb, kb, vb, rtab);
  vtr_k<<<dim3(32, 32), 256, 0, stream>>>(vb, vt);
  attn_k<<<dim3(512), 256, 0, stream>>>(qb, kb, vt, yh);
  gemm_bt<1><<<dim3(8, 32), 256, 0, stream>>>(yh, wo_b, 4096, 1024, 1024,
                                              x2, x, nullptr, nullptr, nullptr, nullptr);
  rms_k<<<4096, 256, 0, stream>>>(x2, g2, yb);
  ffn_k<<<dim3(512), 512, 0, stream>>>(yb, w1_b, w3_b, hb);
  gemm_sk<<<dim3(8, 32, 2), 256, 0, stream>>>(hb, w2_b, part);
  red_k<<<4096, 256, 0, stream>>>(x2, part, (float*)d_out);
}

// Round 14
// 267.141 us; speedup vs baseline: 1.0229x; 1.0229x over previous
//
#include <hip/hip_runtime.h>

// TransformerBlock on MI355X — round 13: ffn reverted to r11 (best measured);
// attention KVBLK 64->128 (half the barriers/waits/softmax-reductions per unit
// work, 80KB LDS, still 2 blocks/CU); QKV GEMM XCD m-grouping.

typedef __attribute__((ext_vector_type(8))) short short8;
typedef __attribute__((ext_vector_type(4))) float f32x4;

#define DEV __device__ __forceinline__

DEV unsigned short f2b(float f) {
  unsigned int u = __builtin_bit_cast(unsigned int, f);
  unsigned int r = u + 0x7fffu + ((u >> 16) & 1u);
  return (unsigned short)(r >> 16);
}
DEV float b2f(unsigned short h) {
  return __builtin_bit_cast(float, ((unsigned int)h) << 16);
}
DEV unsigned int cvtpk(float lo, float hi) {
  unsigned int r;
  asm("v_cvt_pk_bf16_f32 %0, %1, %2" : "=v"(r) : "v"(lo), "v"(hi));
  return r;
}
DEV f32x4 MFMA(short8 a, short8 b, f32x4 c) {
  return __builtin_amdgcn_mfma_f32_16x16x32_bf16(a, b, c, 0, 0, 0);
}
DEV void gload16(const void* g, void* lds) {
  __builtin_amdgcn_global_load_lds((const __attribute__((address_space(1))) void*)g,
                                   (__attribute__((address_space(3))) void*)lds, 16, 0, 0);
}

// ---------------- fused preprocessing: 5x f32->bf16 cvt + RoPE table + RMSNorm(x,g1) ----------------
__global__ __launch_bounds__(256) void prep_k(
    const float* __restrict__ wqkv, const float* __restrict__ wo,
    const float* __restrict__ w1, const float* __restrict__ w3,
    const float* __restrict__ w2,
    unsigned short* __restrict__ wqkv_b, unsigned short* __restrict__ wo_b,
    unsigned short* __restrict__ w1_b, unsigned short* __restrict__ w3_b,
    unsigned short* __restrict__ w2_b,
    float2* __restrict__ rtab,
    const float* __restrict__ x, const float* __restrict__ g1,
    unsigned short* __restrict__ yb) {
  const int bid = blockIdx.x;
  const int t = threadIdx.x;
  if (bid < 16384) {  // weight conversions
    const float* src;
    unsigned short* dst;
    int base;
    if (bid < 3072) { src = wqkv; dst = wqkv_b; base = bid; }
    else if (bid < 4096) { src = wo; dst = wo_b; base = bid - 3072; }
    else if (bid < 8192) { src = w1; dst = w1_b; base = bid - 4096; }
    else if (bid < 12288) { src = w3; dst = w3_b; base = bid - 8192; }
    else { src = w2; dst = w2_b; base = bid - 12288; }
    const int i = (base * 256 + t) * 4;
    float4 v = *(const float4*)(src + i);
    ushort4 o;
    o.x = f2b(v.x); o.y = f2b(v.y); o.z = f2b(v.z); o.w = f2b(v.w);
    *(ushort4*)(dst + i) = o;
  } else if (bid < 16640) {  // RoPE table
    const int i = (bid - 16384) * 256 + t;
    const int lt = i >> 5, pr = i & 31;
    const float invf = __expf((float)pr * -0.28782313662425572f);
    const float ang = (float)lt * invf;
    float sn, cs;
    sincosf(ang, &sn, &cs);
    rtab[i] = make_float2(cs, sn);
  } else {  // RMSNorm(x, g1) -> yb
    const int row = bid - 16640;
    const float4 v = *(const float4*)(x + (size_t)row * 1024 + t * 4);
    float ss = v.x * v.x + v.y * v.y + v.z * v.z + v.w * v.w;
#pragma unroll
    for (int m = 32; m >= 1; m >>= 1) ss += __shfl_xor(ss, m, 64);
    __shared__ float red[4];
    if ((t & 63) == 0) red[t >> 6] = ss;
    __syncthreads();
    float tot = red[0] + red[1] + red[2] + red[3];
    float inv = rsqrtf(tot * (1.0f / 1024.0f) + 1e-5f);
    ushort4 o;
    o.x = f2b(v.x * inv * g1[t * 4 + 0]);
    o.y = f2b(v.y * inv * g1[t * 4 + 1]);
    o.z = f2b(v.z * inv * g1[t * 4 + 2]);
    o.w = f2b(v.w * inv * g1[t * 4 + 3]);
    *(ushort4*)(yb + (size_t)row * 1024 + t * 4) = o;
  }
}

// ---------------- RMSNorm: f32 in, bf16 out (rows of 1024) ----------------
__global__ __launch_bounds__(256) void rms_k(const float* __restrict__ x,
                                             const float* __restrict__ g,
                                             unsigned short* __restrict__ out) {
  const int row = blockIdx.x;
  const int t = threadIdx.x;
  const float4 v = *(const float4*)(x + (size_t)row * 1024 + t * 4);
  float ss = v.x * v.x + v.y * v.y + v.z * v.z + v.w * v.w;
#pragma unroll
  for (int m = 32; m >= 1; m >>= 1) ss += __shfl_xor(ss, m, 64);
  __shared__ float red[4];
  if ((t & 63) == 0) red[t >> 6] = ss;
  __syncthreads();
  float tot = red[0] + red[1] + red[2] + red[3];
  float inv = rsqrtf(tot * (1.0f / 1024.0f) + 1e-5f);
  ushort4 o;
  o.x = f2b(v.x * inv * g[t * 4 + 0]);
  o.y = f2b(v.y * inv * g[t * 4 + 1]);
  o.z = f2b(v.z * inv * g[t * 4 + 2]);
  o.w = f2b(v.w * inv * g[t * 4 + 3]);
  *(ushort4*)(out + (size_t)row * 1024 + t * 4) = o;
}

// ---------------- pipelined 128² GEMM: C[M][N] = A[M][K] * B[N][K]^T ----------------
// MODE 0: QKV scatter + RoPE (flat grid 768, XCD m-grouping); Q pre-scaled.
// MODE 1: outF = resid + acc (f32), XCD m-grouping (grid (8,32)).
template <int MODE>
__global__ __launch_bounds__(256, 3) void gemm_bt(
    const unsigned short* __restrict__ A, const unsigned short* __restrict__ B0,
    int M, int N, int K,
    float* __restrict__ outF, const float* __restrict__ resid,
    unsigned short* __restrict__ q, unsigned short* __restrict__ k2,
    unsigned short* __restrict__ v,
    const float2* __restrict__ rtab) {
  __shared__ __align__(16) unsigned short As[2][128 * 32];
  __shared__ __align__(16) unsigned short Bs[2][128 * 32];
  const int t = threadIdx.x;
  const int wv = t >> 6, ln = t & 63;
  const int l15 = ln & 15, grp = ln >> 4;
  const int wr = wv >> 1, wc = wv & 1;
  int m0, n0;
  if constexpr (MODE == 1) {
    const int d = blockIdx.y * 8 + blockIdx.x;
    const int xcd = d & 7, j = d >> 3;
    m0 = (xcd * 4 + (j >> 3)) * 128;
    n0 = (j & 7) * 128;
  } else {
    // flat grid 768: same-m blocks grouped on one XCD
    const int d = blockIdx.x;
    const int xcd = d & 7, qd = d >> 3;
    m0 = (xcd + 8 * (qd / 24)) * 128;
    n0 = (qd % 24) * 128;
  }

  const char* sA0 = (const char*)A + ((size_t)(m0 + (t >> 2)) * K + (t & 3) * 8) * 2;
  const char* sA1 = (const char*)A + ((size_t)(m0 + 64 + (t >> 2)) * K + (t & 3) * 8) * 2;
  const char* sB0 = (const char*)B0 + ((size_t)(n0 + (t >> 2)) * K + (t & 3) * 8) * 2;
  const char* sB1 = (const char*)B0 + ((size_t)(n0 + 64 + (t >> 2)) * K + (t & 3) * 8) * 2;

  f32x4 acc[4][4];
#pragma unroll
  for (int mm = 0; mm < 4; ++mm)
#pragma unroll
    for (int nn = 0; nn < 4; ++nn) acc[mm][nn] = (f32x4){0.f, 0.f, 0.f, 0.f};

  const int KT = K >> 5;
  gload16(sA0, (char*)As[0] + wv * 1024);
  gload16(sA1, (char*)As[0] + 4096 + wv * 1024);
  gload16(sB0, (char*)Bs[0] + wv * 1024);
  gload16(sB1, (char*)Bs[0] + 4096 + wv * 1024);

#pragma unroll 1
  for (int kt = 0; kt < KT; ++kt) {
    const int par = kt & 1;
    const size_t ko = (size_t)((kt + 1 < KT) ? (kt + 1) : kt) * 64;  // bytes
    gload16(sA0 + ko, (char*)As[par ^ 1] + wv * 1024);
    gload16(sA1 + ko, (char*)As[par ^ 1] + 4096 + wv * 1024);
    gload16(sB0 + ko, (char*)Bs[par ^ 1] + wv * 1024);
    gload16(sB1 + ko, (char*)Bs[par ^ 1] + 4096 + wv * 1024);
    asm volatile("s_waitcnt vmcnt(4)" ::: "memory");
    __builtin_amdgcn_s_barrier();
    const unsigned short* Ab = As[par];
    const unsigned short* Bb = Bs[par];
    short8 af[4], bf0[4];
#pragma unroll
    for (int mm = 0; mm < 4; ++mm)
      af[mm] = *(const short8*)&Ab[(wr * 64 + mm * 16 + l15) * 32 + grp * 8];
#pragma unroll
    for (int nn = 0; nn < 4; ++nn)
      bf0[nn] = *(const short8*)&Bb[(wc * 64 + nn * 16 + l15) * 32 + grp * 8];
#pragma unroll
    for (int mm = 0; mm < 4; ++mm)
#pragma unroll
      for (int nn = 0; nn < 4; ++nn) acc[mm][nn] = MFMA(af[mm], bf0[nn], acc[mm][nn]);
    __builtin_amdgcn_s_barrier();
  }

#pragma unroll
  for (int mm = 0; mm < 4; ++mm)
#pragma unroll
    for (int nn = 0; nn < 4; ++nn)
#pragma unroll
      for (int j = 0; j < 4; ++j) {
        const int r = m0 + wr * 64 + mm * 16 + grp * 4 + j;
        const int c = n0 + wc * 64 + nn * 16 + l15;
        float val = acc[mm][nn][j];
        if constexpr (MODE == 0) {
          const int mat = c >> 10;
          const int rem = c & 1023;
          const int hh = rem >> 6;
          const int dh = rem & 63;
          const int bt = r >> 11;
          const int lt = r & 2047;
          float outv = val;
          if (mat < 2) {  // RoPE on q,k via table
            const float partner = __shfl_xor(val, 1, 64);
            const float2 cs = rtab[lt * 32 + (dh >> 1)];
            outv = (dh & 1) ? (val * cs.x + partner * cs.y) : (val * cs.x - partner * cs.y);
          }
          if (mat == 0) outv *= 0.18033688011112042f;  // 0.125 * log2(e)
          unsigned short* dst = (mat == 0) ? q : ((mat == 1) ? k2 : v);
          dst[((size_t)(bt * 16 + hh) * 2048 + lt) * 64 + dh] = f2b(outv);
        } else {
          const size_t idx = (size_t)r * N + c;
          outF[idx] = resid[idx] + val;
        }
      }
}

// ---------------- W2 split-K chunk GEMM (S=2, chunk K=2048) ----------------
__global__ __launch_bounds__(256, 3) void gemm_sk(
    const unsigned short* __restrict__ A, const unsigned short* __restrict__ B0,
    unsigned short* __restrict__ part) {
  __shared__ __align__(16) unsigned short As[2][128 * 32];
  __shared__ __align__(16) unsigned short Bs[2][128 * 32];
  const int t = threadIdx.x;
  const int wv = t >> 6, ln = t & 63;
  const int l15 = ln & 15, grp = ln >> 4;
  const int wr = wv >> 1, wc = wv & 1;
  const int d = blockIdx.y * 8 + blockIdx.x;
  const int xcd = d & 7, j = d >> 3;
  const int m0 = (xcd * 4 + (j >> 3)) * 128;
  const int n0 = (j & 7) * 128;
  const size_t kbase = (size_t)blockIdx.z * 2048;

  const char* sA0 = (const char*)A + ((size_t)(m0 + (t >> 2)) * 4096 + kbase + (t & 3) * 8) * 2;
  const char* sA1 = (const char*)A + ((size_t)(m0 + 64 + (t >> 2)) * 4096 + kbase + (t & 3) * 8) * 2;
  const char* sB0 = (const char*)B0 + ((size_t)(n0 + (t >> 2)) * 4096 + kbase + (t & 3) * 8) * 2;
  const char* sB1 = (const char*)B0 + ((size_t)(n0 + 64 + (t >> 2)) * 4096 + kbase + (t & 3) * 8) * 2;

  f32x4 acc[4][4];
#pragma unroll
  for (int mm = 0; mm < 4; ++mm)
#pragma unroll
    for (int nn = 0; nn < 4; ++nn) acc[mm][nn] = (f32x4){0.f, 0.f, 0.f, 0.f};

  gload16(sA0, (char*)As[0] + wv * 1024);
  gload16(sA1, (char*)As[0] + 4096 + wv * 1024);
  gload16(sB0, (char*)Bs[0] + wv * 1024);
  gload16(sB1, (char*)Bs[0] + 4096 + wv * 1024);

#pragma unroll 1
  for (int kt = 0; kt < 64; ++kt) {
    const int par = kt & 1;
    const size_t ko = (size_t)((kt + 1 < 64) ? (kt + 1) : kt) * 64;
    gload16(sA0 + ko, (char*)As[par ^ 1] + wv * 1024);
    gload16(sA1 + ko, (char*)As[par ^ 1] + 4096 + wv * 1024);
    gload16(sB0 + ko, (char*)Bs[par ^ 1] + wv * 1024);
    gload16(sB1 + ko, (char*)Bs[par ^ 1] + 4096 + wv * 1024);
    asm volatile("s_waitcnt vmcnt(4)" ::: "memory");
    __builtin_amdgcn_s_barrier();
    const unsigned short* Ab = As[par];
    const unsigned short* Bb = Bs[par];
    short8 af[4], bf0[4];
#pragma unroll
    for (int mm = 0; mm < 4; ++mm)
      af[mm] = *(const short8*)&Ab[(wr * 64 + mm * 16 + l15) * 32 + grp * 8];
#pragma unroll
    for (int nn = 0; nn < 4; ++nn)
      bf0[nn] = *(const short8*)&Bb[(wc * 64 + nn * 16 + l15) * 32 + grp * 8];
#pragma unroll
    for (int mm = 0; mm < 4; ++mm)
#pragma unroll
      for (int nn = 0; nn < 4; ++nn) acc[mm][nn] = MFMA(af[mm], bf0[nn], acc[mm][nn]);
    __builtin_amdgcn_s_barrier();
  }

  unsigned short* pz = part + (size_t)blockIdx.z * 4194304;
#pragma unroll
  for (int mm = 0; mm < 4; ++mm)
#pragma unroll
    for (int nn = 0; nn < 4; ++nn)
#pragma unroll
      for (int j = 0; j < 4; ++j) {
        const int r = m0 + wr * 64 + mm * 16 + grp * 4 + j;
        const int c = n0 + wc * 64 + nn * 16 + l15;
        pz[(size_t)r * 1024 + c] = f2b(acc[mm][nn][j]);
      }
}

// ---------------- reduce: out = x2 + sum of 2 bf16 partials ----------------
__global__ __launch_bounds__(256) void red_k(const float* __restrict__ x2,
                                             const unsigned short* __restrict__ part,
                                             float* __restrict__ out) {
  const int i = (blockIdx.x * 256 + threadIdx.x) * 4;
  float4 r = *(const float4*)(x2 + i);
#pragma unroll
  for (int z = 0; z < 2; ++z) {
    const ushort4 p = *(const ushort4*)(part + (size_t)z * 4194304 + i);
    r.x += b2f(p.x);
    r.y += b2f(p.y);
    r.z += b2f(p.z);
    r.w += b2f(p.w);
  }
  *(float4*)(out + i) = r;
}

// ---------------- FFN dual-GEMM: 256x256(Bv) tile, 4-phase, unpinned (r11 form) ----------------
__global__ __launch_bounds__(512, 2) void ffn_k(
    const unsigned short* __restrict__ A, const unsigned short* __restrict__ B0,
    const unsigned short* __restrict__ B1, unsigned short* __restrict__ outH) {
  __shared__ __align__(16) char Asm[2][32768];
  __shared__ __align__(16) char Bsm[2][32768];
  const int t = threadIdx.x;
  const int wid = t >> 6, lane = t & 63;
  const int l15 = lane & 15, grp = lane >> 4;
  const int wr = wid >> 2, wc = wid & 3;
  const int d = blockIdx.x;
  const int xcd = d & 7, r8 = d >> 3;
  const int m0 = (r8 >> 2) * 256;
  const int n0 = (xcd * 4 + (r8 & 3)) * 256;

  const char* srcA0;
  const char* srcB0;
  {
    const int lb = t * 16;
    const int r = lb >> 7;
    const int sw = (((lb >> 4) & 7) * 16) ^ ((r & 7) << 4);
    srcA0 = (const char*)A + (size_t)(m0 + r) * 2048 + sw;
    const int R = n0 + r;
    const unsigned short* bsrc = ((R >> 4) & 1) ? B1 : B0;
    const int br = ((R >> 5) << 4) + (R & 15);
    srcB0 = (const char*)bsrc + (size_t)br * 2048 + sw;
  }
  char* const ldsA = (char*)Asm + wid * 1024;
  char* const ldsB = (char*)Bsm + wid * 1024;

  f32x4 acc[8][4];
#pragma unroll
  for (int m = 0; m < 8; ++m)
#pragma unroll
    for (int n = 0; n < 4; ++n) acc[m][n] = (f32x4){0.f, 0.f, 0.f, 0.f};

  gload16(srcA0 + 0 * 131072, ldsA + 0 * 8192);
  gload16(srcA0 + 1 * 131072, ldsA + 1 * 8192);
  gload16(srcB0 + 0 * 65536, ldsB + 0 * 8192);
  gload16(srcB0 + 1 * 65536, ldsB + 1 * 8192);
  gload16(srcB0 + 2 * 65536, ldsB + 2 * 8192);
  gload16(srcB0 + 3 * 65536, ldsB + 3 * 8192);
  gload16(srcA0 + 2 * 131072, ldsA + 2 * 8192);
  gload16(srcA0 + 3 * 131072, ldsA + 3 * 8192);

  const int rA0 = wr * 64 + l15;
  const int rB0 = wc * 32 + l15;

#pragma unroll 1
  for (int kt = 0; kt < 16; ++kt) {
    const int cb = kt & 1;
    const size_t koff = (size_t)((kt + 1 < 16) ? (kt + 1) : kt) * 128;
    const char* Ab = Asm[cb];
    const char* Bb = Bsm[cb];
    const int nb = (cb ^ 1) * 32768;

    short8 a0[2][4], a1[2][4], b0[2][2], b1[2][2];

    gload16(srcA0 + 0 * 131072 + koff, ldsA + nb + 0 * 8192);
    gload16(srcA0 + 1 * 131072 + koff, ldsA + nb + 1 * 8192);
    asm volatile("s_waitcnt vmcnt(4)" ::: "memory");
    __builtin_amdgcn_s_barrier();
#pragma unroll
    for (int ks = 0; ks < 2; ++ks)
#pragma unroll
      for (int m = 0; m < 4; ++m) {
        const int r = rA0 + m * 16;
        a0[ks][m] = *(const short8*)(Ab + r * 128 + ((ks * 64 + grp * 16) ^ ((r & 7) << 4)));
      }
#pragma unroll
    for (int ks = 0; ks < 2; ++ks)
#pragma unroll
      for (int n = 0; n < 2; ++n) {
        const int r = rB0 + n * 16;
        b0[ks][n] = *(const short8*)(Bb + r * 128 + ((ks * 64 + grp * 16) ^ ((r & 7) << 4)));
      }
#pragma unroll
    for (int ks = 0; ks < 2; ++ks)
#pragma unroll
      for (int n = 0; n < 2; ++n) {
        const int r = 128 + rB0 + n * 16;
        b1[ks][n] = *(const short8*)(Bb + r * 128 + ((ks * 64 + grp * 16) ^ ((r & 7) << 4)));
      }
    __builtin_amdgcn_s_setprio(1);
#pragma unroll
    for (int ks = 0; ks < 2; ++ks)
#pragma unroll
      for (int m = 0; m < 4; ++m)
#pragma unroll
        for (int n = 0; n < 2; ++n) acc[m][n] = MFMA(a0[ks][m], b0[ks][n], acc[m][n]);
    __builtin_amdgcn_s_setprio(0);

    gload16(srcB0 + 0 * 65536 + koff, ldsB + nb + 0 * 8192);
    gload16(srcB0 + 1 * 65536 + koff, ldsB + nb + 1 * 8192);
    gload16(srcB0 + 2 * 65536 + koff, ldsB + nb + 2 * 8192);
    gload16(srcB0 + 3 * 65536 + koff, ldsB + nb + 3 * 8192);
    asm volatile("s_waitcnt vmcnt(6)" ::: "memory");
    __builtin_amdgcn_s_barrier();
#pragma unroll
    for (int ks = 0; ks < 2; ++ks)
#pragma unroll
      for (int m = 0; m < 4; ++m) {
        const int r = 128 + rA0 + m * 16;
        a1[ks][m] = *(const short8*)(Ab + r * 128 + ((ks * 64 + grp * 16) ^ ((r & 7) << 4)));
      }
    __builtin_amdgcn_s_setprio(1);
#pragma unroll
    for (int ks = 0; ks < 2; ++ks)
#pragma unroll
      for (int m = 0; m < 4; ++m)
#pragma unroll
        for (int n = 0; n < 2; ++n) acc[m][2 + n] = MFMA(a0[ks][m], b1[ks][n], acc[m][2 + n]);
    __builtin_amdgcn_s_setprio(0);

    gload16(srcA0 + 2 * 131072 + koff, ldsA + nb + 2 * 8192);
    gload16(srcA0 + 3 * 131072 + koff, ldsA + nb + 3 * 8192);
    __builtin_amdgcn_s_barrier();
    __builtin_amdgcn_s_setprio(1);
#pragma unroll
    for (int ks = 0; ks < 2; ++ks)
#pragma unroll
      for (int m = 0; m < 4; ++m)
#pragma unroll
        for (int n = 0; n < 2; ++n) acc[4 + m][2 + n] = MFMA(a1[ks][m], b1[ks][n], acc[4 + m][2 + n]);
    __builtin_amdgcn_s_setprio(0);

    __builtin_amdgcn_s_barrier();
    __builtin_amdgcn_s_setprio(1);
#pragma unroll
    for (int ks = 0; ks < 2; ++ks)
#pragma unroll
      for (int m = 0; m < 4; ++m)
#pragma unroll
        for (int n = 0; n < 2; ++n) acc[4 + m][n] = MFMA(a1[ks][m], b0[ks][n], acc[4 + m][n]);
    __builtin_amdgcn_s_setprio(0);
  }

#pragma unroll
  for (int mh = 0; mh < 2; ++mh)
#pragma unroll
    for (int m = 0; m < 4; ++m)
#pragma unroll
      for (int nh = 0; nh < 2; ++nh)
#pragma unroll
        for (int j = 0; j < 4; ++j) {
          const int row = m0 + mh * 128 + wr * 64 + m * 16 + grp * 4 + j;
          const int ch = (n0 >> 1) + nh * 64 + wc * 16 + l15;
          const float a1v = acc[mh * 4 + m][nh * 2 + 0][j];
          const float a3v = acc[mh * 4 + m][nh * 2 + 1][j];
          const float hval = a1v / (1.0f + __expf(-a1v)) * a3v;
          outH[(size_t)row * 4096 + ch] = f2b(hval);
        }
}

// ---------------- V transpose: vb[bh][lt][dh] -> vt[bh][dh][lt] ----------------
__global__ __launch_bounds__(256) void vtr_k(const unsigned short* __restrict__ v,
                                             unsigned short* __restrict__ vt) {
  __shared__ __align__(16) unsigned short tile[64][72];
  const int bh = blockIdx.y;
  const int lt0 = blockIdx.x * 64;
  const int t = threadIdx.x;
  const int r = t >> 2;
  const int c0 = (t & 3) * 16;
  const unsigned short* src = v + ((size_t)bh * 2048 + lt0 + r) * 64 + c0;
  *(short8*)&tile[r][c0] = *(const short8*)src;
  *(short8*)&tile[r][c0 + 8] = *(const short8*)(src + 8);
  __syncthreads();
  unsigned short outv[16];
#pragma unroll
  for (int i = 0; i < 16; ++i) outv[i] = tile[c0 + i][r];
  unsigned short* dst = vt + ((size_t)bh * 64 + r) * 2048 + lt0 + c0;
  *(short8*)dst = *(short8*)&outv[0];
  *(short8*)(dst + 8) = *(short8*)&outv[8];
}

// ---------------- causal flash attention: 4 waves, QBLK=64, KVBLK=128 ----------------
// Swapped QK^T (lane-local base-2 softmax), cvt_pk P-pack, defer-rescale.
// KV tile 128: K [128kv][64d] (128B rows), V^T [64d][128kv] (256B rows),
// per-wave P [16q][128k] (256B rows). All rows XOR-swizzled in byte bits 4-6.
// LDS 80KB -> 2 blocks/CU. 8 staging shots/tile, vmcnt(8), 2 barriers/tile.
__global__ __launch_bounds__(256) void attn_k(const unsigned short* __restrict__ qb,
                                              const unsigned short* __restrict__ kb,
                                              const unsigned short* __restrict__ vt,
                                              unsigned short* __restrict__ yh) {
  const int dd = blockIdx.x;  // 512 blocks: all 16 pairs of a head on one XCD
  const int xcd = dd & 7, idx = dd >> 3;
  const int bh = xcd + 8 * (idx & 3);
  const int pair = idx >> 2;  // 0..15
  const int t = threadIdx.x;
  const int w = t >> 6, lane = t & 63;
  const int l15 = lane & 15, grp = lane >> 4;

  __shared__ __align__(16) char Ks[2][16384];
  __shared__ __align__(16) char Vs[2][16384];
  __shared__ __align__(16) char Ps[16384];
  char* Pw = Ps + w * 4096;

  const char* kg = (const char*)kb + (size_t)bh * 262144;
  const char* vg = (const char*)vt + (size_t)bh * 262144;

  // staging: shot s covers LDS bytes lb = s*4096 + t*16
  const char* srcK[4];
  const char* srcV[4];
#pragma unroll
  for (int s = 0; s < 4; ++s) {
    const int lb = s * 4096 + t * 16;
    const int rK = lb >> 7;                       // K row (128B rows)
    const int oK = (lb & 0x70) ^ ((rK & 7) << 4);
    srcK[s] = kg + rK * 128 + oK;
    const int rV = lb >> 8;                       // V^T row (256B rows)
    const int oV = (lb & 0xF0) ^ ((rV & 7) << 4);
    srcV[s] = vg + (size_t)rV * 4096 + oV;
  }

  const int bq = bh >> 4, hh = bh & 15;

#pragma unroll 1
  for (int half = 0; half < 2; ++half) {
    const int qblk = half ? pair : (31 - pair);
    const int qw = qblk * 64 + w * 16;

    const unsigned short* qp = qb + ((size_t)bh * 2048 + qw) * 64;
    const short8 qf0 = *(const short8*)(qp + l15 * 64 + grp * 8);
    const short8 qf1 = *(const short8*)(qp + l15 * 64 + 32 + grp * 8);

    f32x4 o[4];
#pragma unroll
    for (int d = 0; d < 4; ++d) o[d] = (f32x4){0.f, 0.f, 0.f, 0.f};
    float mrun = -3.0e38f, lrun = 0.f;  // per-lane: q = qw + l15

    const int nkt = (qblk + 2) >> 1;  // ceil((qblk+1)*64 / 128)

    __syncthreads();
#pragma unroll
    for (int s = 0; s < 4; ++s) {
      gload16(srcK[s], Ks[0] + s * 4096 + w * 1024);
      gload16(srcV[s], Vs[0] + s * 4096 + w * 1024);
    }

#pragma unroll 1
    for (int kt = 0; kt < nkt; ++kt) {
      const int par = kt & 1;
      const int ktn = (kt + 1 < nkt) ? (kt + 1) : kt;
#pragma unroll
      for (int s = 0; s < 4; ++s) {
        gload16(srcK[s] + (size_t)ktn * 16384, Ks[par ^ 1] + s * 4096 + w * 1024);
        gload16(srcV[s] + (size_t)ktn * 256, Vs[par ^ 1] + s * 4096 + w * 1024);
      }
      asm volatile("s_waitcnt vmcnt(8)" ::: "memory");
      __builtin_amdgcn_s_barrier();

      const char* Kc = Ks[par];
      const char* Vc = Vs[par];

      // swapped QK^T: st[c][j] = S^T[k = 16c + 4*grp + j][q = l15]
      f32x4 st[8];
#pragma unroll
      for (int c = 0; c < 8; ++c) {
        const int r = c * 16 + l15;
        const int xr = (r & 7) << 4;
        const short8 kf0 = *(const short8*)(Kc + r * 128 + ((grp * 16) ^ xr));
        const short8 kf1 = *(const short8*)(Kc + r * 128 + ((64 + grp * 16) ^ xr));
        f32x4 z = (f32x4){0.f, 0.f, 0.f, 0.f};
        __builtin_amdgcn_s_setprio(1);
        z = MFMA(kf0, qf0, z);
        z = MFMA(kf1, qf1, z);
        __builtin_amdgcn_s_setprio(0);
        st[c] = z;
      }

      const bool diag = (kt * 128 + 127 > qw);  // per-wave
      const int qg = qw + l15;
      float tm = -3.0e38f;
#pragma unroll
      for (int c = 0; c < 8; ++c)
#pragma unroll
        for (int j = 0; j < 4; ++j) {
          float x = st[c][j];
          if (diag) {
            const int kg2 = kt * 128 + c * 16 + grp * 4 + j;
            if (kg2 > qg) x = -3.0e38f;
          }
          st[c][j] = x;
          tm = fmaxf(tm, x);
        }
      tm = fmaxf(tm, __shfl_xor(tm, 16, 64));
      tm = fmaxf(tm, __shfl_xor(tm, 32, 64));

      const float mold = mrun;
      const bool need = tm > mold;
      mrun = fmaxf(mold, tm);
      const float aown = need ? __builtin_amdgcn_exp2f(mold - mrun) : 1.0f;
      if (__any(need)) {  // wave-uniform
        float am[4];
#pragma unroll
        for (int j = 0; j < 4; ++j) am[j] = __shfl(aown, grp * 4 + j, 64);
#pragma unroll
        for (int d = 0; d < 4; ++d)
#pragma unroll
          for (int j = 0; j < 4; ++j) o[d][j] *= am[j];
      }

      float rs = 0.f;
      uint2 pk[8];
#pragma unroll
      for (int c = 0; c < 8; ++c) {
        const float p0 = __builtin_amdgcn_exp2f(st[c][0] - mrun);
        const float p1 = __builtin_amdgcn_exp2f(st[c][1] - mrun);
        const float p2 = __builtin_amdgcn_exp2f(st[c][2] - mrun);
        const float p3 = __builtin_amdgcn_exp2f(st[c][3] - mrun);
        rs += (p0 + p1) + (p2 + p3);
        pk[c].x = cvtpk(p0, p1);
        pk[c].y = cvtpk(p2, p3);
      }
      rs += __shfl_xor(rs, 16, 64);
      rs += __shfl_xor(rs, 32, 64);
      lrun = lrun * aown + rs;

      // write P row q=l15 (256B row): quad (4c+grp) at byte (32c+8grp)^xp
      const int xp = (l15 & 7) << 4;
      char* prow = Pw + l15 * 256;
#pragma unroll
      for (int c = 0; c < 8; ++c)
        *(uint2*)(prow + ((32 * c + 8 * grp) ^ xp)) = pk[c];

      // PV: A = P rows (4 ks-fragments), B = V^T rows
      short8 pa[4];
#pragma unroll
      for (int ks = 0; ks < 4; ++ks)
        pa[ks] = *(const short8*)(prow + ((ks * 64 + grp * 16) ^ xp));
#pragma unroll
      for (int db = 0; db < 4; ++db) {
        const int rv = db * 16 + l15;
        const int xv = (rv & 7) << 4;
        __builtin_amdgcn_s_setprio(1);
#pragma unroll
        for (int ks = 0; ks < 4; ++ks) {
          const short8 vf = *(const short8*)(Vc + rv * 256 + ((ks * 64 + grp * 16) ^ xv));
          o[db] = MFMA(pa[ks], vf, o[db]);
        }
        __builtin_amdgcn_s_setprio(0);
      }
      __builtin_amdgcn_s_barrier();
    }

    float lr[4];
#pragma unroll
    for (int j = 0; j < 4; ++j) lr[j] = __shfl(lrun, grp * 4 + j, 64);
#pragma unroll
    for (int db = 0; db < 4; ++db)
#pragma unroll
      for (int j = 0; j < 4; ++j) {
        const float valo = o[db][j] / lr[j];
        const size_t rowo = (size_t)bq * 2048 + qw + grp * 4 + j;
        yh[rowo * 1024 + hh * 64 + db * 16 + l15] = f2b(valo);
      }
  }
}

extern "C" void kernel_launch(void* const* d_in, const int* in_sizes, int n_in,
                              void* d_out, int out_size, void* d_ws, size_t ws_size,
                              hipStream_t stream) {
  const float* x = (const float*)d_in[0];
  const float* wqkv = (const float*)d_in[1];
  const float* wo = (const float*)d_in[2];
  const float* w1 = (const float*)d_in[3];
  const float* w2 = (const float*)d_in[4];
  const float* w3 = (const float*)d_in[5];
  const float* g1 = (const float*)d_in[6];
  const float* g2 = (const float*)d_in[7];

  // Workspace layout (88 MB), lifetimes annotated:
  char* ws = (char*)d_ws;
  unsigned short* wqkv_b = (unsigned short*)(ws + 0);         // 6 MB  [prep -> qkv]
  unsigned short* wo_b = (unsigned short*)(ws + 6291456);     // 2 MB  [prep -> wo]
  unsigned short* w1_b = (unsigned short*)(ws + 8388608);     // 8 MB  [prep -> ffn]
  unsigned short* w3_b = (unsigned short*)(ws + 16777216);    // 8 MB  [prep -> ffn]
  unsigned short* yb = (unsigned short*)(ws + 25165824);      // 8 MB  [prep/rms -> qkv/ffn]
  float* x2 = (float*)(ws + 33554432);                        // 16 MB [wo -> red]
  float2* rtab = (float2*)(ws + 33554432);                    // aliases x2, dead before wo
  unsigned short* w2_b = (unsigned short*)(ws + 50331648);    // 8 MB  [prep -> gemm_sk]
  unsigned short* qb = (unsigned short*)(ws + 58720256);      // 8 MB  [qkv -> attn]
  unsigned short* kb = (unsigned short*)(ws + 67108864);      // 8 MB  [qkv -> attn]
  unsigned short* vb = (unsigned short*)(ws + 75497472);      // 8 MB  [qkv -> vtr]
  unsigned short* vt = (unsigned short*)(ws + 83886080);      // 8 MB  [vtr -> attn]
  unsigned short* yh = vb;                                    // attn out reuses dead vb
  unsigned short* hb = (unsigned short*)(ws + 58720256);      // 32 MB [ffn -> gemm_sk], over dead q/k/v/vt
  unsigned short* part = (unsigned short*)(ws + 0);           // 16 MB [gemm_sk -> red], over dead weights
  if (ws_size < 92274688) return;

  prep_k<<<20736, 256, 0, stream>>>(wqkv, wo, w1, w3, w2,
                                    wqkv_b, wo_b, w1_b, w3_b, w2_b,
                                    rtab, x, g1, yb);
  gemm_bt<0><<<dim3(768), 256, 0, stream>>>(yb, wqkv_b, 4096, 3072, 1024,
                                            nullptr, nullptr, qb, kb, vb, rtab);
  vtr_k<<<dim3(32, 32), 256, 0, stream>>>(vb, vt);
  attn_k<<<dim3(512), 256, 0, stream>>>(qb, kb, vt, yh);
  gemm_bt<1><<<dim3(8, 32), 256, 0, stream>>>(yh, wo_b, 4096, 1024, 1024,
                                              x2, x, nullptr, nullptr, nullptr, nullptr);
  rms_k<<<4096, 256, 0, stream>>>(x2, g2, yb);
  ffn_k<<<dim3(512), 512, 0, stream>>>(yb, w1_b, w3_b, hb);
  gemm_sk<<<dim3(8, 32, 2), 256, 0, stream>>>(hb, w2_b, part);
  red_k<<<4096, 256, 0, stream>>>(x2, part, (float*)d_out);
}